// Round 5
// baseline (561.771 us; speedup 1.0000x reference)
//
#include <hip/hip_runtime.h>
#include <hip/hip_bf16.h>

// Problem constants
#define N_NODES 2048
#define EMB 16
#define NT 12
#define BT 192
#define C_COLS 12288           // BT*64
#define TD 768                 // NT*64, per-(b,node) row length in x
#define BSTRIDE (N_NODES * TD) // per-b stride in x
#define KDIM 2048              // contraction dim (nodes)

typedef unsigned short u16;
typedef unsigned int u32;
typedef __attribute__((ext_vector_type(8))) __bf16 bf16x8;
typedef __attribute__((ext_vector_type(8))) u16 u16x8;
typedef __attribute__((ext_vector_type(4))) float f32x4;

__device__ __forceinline__ u16 f2bfu(float f) { // RNE fp32 -> bf16 bits
    u32 u = __float_as_uint(f);
    return (u16)((u + 0x7FFFu + ((u >> 16) & 1u)) >> 16);
}
__device__ __forceinline__ float bfu2f(u16 h) {
    return __uint_as_float(((u32)h) << 16);
}

// async 16B global->LDS (lds dest = wave-uniform base + lane*16)
__device__ __forceinline__ void gl2lds16(const void* g, void* l) {
    __builtin_amdgcn_global_load_lds(
        (const __attribute__((address_space(1))) u32*)g,
        (__attribute__((address_space(3))) u32*)l, 16, 0, 0);
}

// chunk swizzle: permute 16B chunks within each 128B (64-elem) block by row&7
__device__ __forceinline__ int cswz(int col, int row) {
    return (col & ~63) | ((((col >> 3) ^ row) & 7) << 3) | (col & 7);
}

// ---------------------------------------------------------------------------
// Kernel 1 (old path): Sb[n][m] = bf16( softmax_m( relu( E[n]·E[m] ) ) )
// ---------------------------------------------------------------------------
__global__ void supports_kernel(const float* __restrict__ E, u16* __restrict__ Sb)
{
    __shared__ float en[EMB];
    __shared__ float red[256];
    const int n = blockIdx.x;
    const int tid = threadIdx.x;
    if (tid < EMB) en[tid] = E[n * EMB + tid];
    __syncthreads();

    float v[8];
    float mx = 0.0f;
    #pragma unroll
    for (int j = 0; j < 8; ++j) {
        const int m = tid + j * 256;
        const float* em = E + m * EMB;
        float acc = 0.f;
        #pragma unroll
        for (int d = 0; d < EMB; ++d) acc += en[d] * em[d];
        acc = fmaxf(acc, 0.f);
        v[j] = acc;
        mx = fmaxf(mx, acc);
    }
    red[tid] = mx;
    __syncthreads();
    for (int s = 128; s > 0; s >>= 1) {
        if (tid < s) red[tid] = fmaxf(red[tid], red[tid + s]);
        __syncthreads();
    }
    mx = red[0];
    __syncthreads();

    float sum = 0.f;
    #pragma unroll
    for (int j = 0; j < 8; ++j) { v[j] = __expf(v[j] - mx); sum += v[j]; }
    red[tid] = sum;
    __syncthreads();
    for (int s = 128; s > 0; s >>= 1) {
        if (tid < s) red[tid] += red[tid + s];
        __syncthreads();
    }
    const float inv = 1.f / red[0];
    #pragma unroll
    for (int j = 0; j < 8; ++j)
        Sb[(size_t)n * KDIM + tid + j * 256] = f2bfu(v[j] * inv);
}

// ---------------------------------------------------------------------------
// Kernel 1b (256-scheme): same, but stores chunk-swizzled by n&7.
// ---------------------------------------------------------------------------
__global__ void supports2_kernel(const float* __restrict__ E, u16* __restrict__ Sb)
{
    __shared__ float en[EMB];
    __shared__ float red[256];
    const int n = blockIdx.x;
    const int tid = threadIdx.x;
    if (tid < EMB) en[tid] = E[n * EMB + tid];
    __syncthreads();

    float v[8];
    float mx = 0.0f;
    #pragma unroll
    for (int j = 0; j < 8; ++j) {
        const int m = tid + j * 256;
        const float* em = E + m * EMB;
        float acc = 0.f;
        #pragma unroll
        for (int d = 0; d < EMB; ++d) acc += en[d] * em[d];
        acc = fmaxf(acc, 0.f);
        v[j] = acc;
        mx = fmaxf(mx, acc);
    }
    red[tid] = mx;
    __syncthreads();
    for (int s = 128; s > 0; s >>= 1) {
        if (tid < s) red[tid] = fmaxf(red[tid], red[tid + s]);
        __syncthreads();
    }
    mx = red[0];
    __syncthreads();

    float sum = 0.f;
    #pragma unroll
    for (int j = 0; j < 8; ++j) { v[j] = __expf(v[j] - mx); sum += v[j]; }
    red[tid] = sum;
    __syncthreads();
    for (int s = 128; s > 0; s >>= 1) {
        if (tid < s) red[tid] += red[tid + s];
        __syncthreads();
    }
    const float inv = 1.f / red[0];
    #pragma unroll
    for (int j = 0; j < 8; ++j) {
        const int m = tid + j * 256;
        Sb[(size_t)n * KDIM + cswz(m, n)] = f2bfu(v[j] * inv);
    }
}

// ---------------------------------------------------------------------------
// strans: SbT'[j][swz(m,j)] = S[m][j]  (reads swizzled Sb', writes swizzled)
// ---------------------------------------------------------------------------
__global__ void strans_kernel(const u16* __restrict__ Sb, u16* __restrict__ SbT)
{
    __shared__ u16 T[64][65];
    const int tid = threadIdx.x;
    const int n0 = blockIdx.y * 64;
    const int j0 = blockIdx.x * 64;
    const int lc = tid & 63;
    const int rg = tid >> 6;
    #pragma unroll
    for (int j = 0; j < 16; ++j) {
        const int r = j * 4 + rg;                 // row n0+r of Sb'
        const u16 vv = Sb[(size_t)(n0 + r) * KDIM + j0 + lc];
        // true col of stored pos (j0+lc) in row n: involution
        const int jt = ((((lc >> 3) ^ (n0 + r)) & 7) << 3) | (lc & 7);
        T[jt][r] = vv;                            // T[jt][r] = S[n0+r][j0+jt]
    }
    __syncthreads();
    #pragma unroll
    for (int j = 0; j < 16; ++j) {
        const int jj = j * 4 + rg;                // out row j0+jj
        const int cs = ((((lc >> 3) ^ (j0 + jj)) & 7) << 3) | (lc & 7);
        SbT[(size_t)(j0 + jj) * KDIM + n0 + cs] = T[jj][lc];
    }
}

// ---------------------------------------------------------------------------
// Kernel 2 (old path): xcast — XbT[c][m] = bf16(x[b][m][r])
// ---------------------------------------------------------------------------
__global__ void xcast_kernel(const float* __restrict__ x, u16* __restrict__ XbT, int c0g)
{
    __shared__ u16 tile[64][65];
    const int tid = threadIdx.x;
    const int cg = c0g + blockIdx.x * 64;
    const int b = cg / TD;
    const int r0 = cg - b * TD;
    const int m0 = blockIdx.y * 64;
    const float* xp = x + (size_t)b * BSTRIDE + (size_t)m0 * TD + r0;

    const int lc = tid & 63;
    const int rg = tid >> 6;
    #pragma unroll
    for (int j = 0; j < 16; ++j) {
        const int mr = j * 4 + rg;
        tile[lc][mr] = f2bfu(xp[(size_t)mr * TD + lc]);
    }
    __syncthreads();
    u16* op = XbT + (size_t)(blockIdx.x * 64) * KDIM + m0;
    #pragma unroll
    for (int j = 0; j < 16; ++j) {
        const int cr = j * 4 + rg;
        op[(size_t)cr * KDIM + lc] = tile[cr][lc];
    }
}

// ---------------------------------------------------------------------------
// Kernel 2b (256-scheme): xcast with chunk-swizzled output (by c&7).
// ---------------------------------------------------------------------------
__global__ void xcast2_kernel(const float* __restrict__ x, u16* __restrict__ XbT)
{
    __shared__ u16 tile[64][65];
    const int tid = threadIdx.x;
    const int cg = blockIdx.x * 64;
    const int b = cg / TD;
    const int r0 = cg - b * TD;
    const int m0 = blockIdx.y * 64;
    const float* xp = x + (size_t)b * BSTRIDE + (size_t)m0 * TD + r0;

    const int lc = tid & 63;
    const int rg = tid >> 6;
    #pragma unroll
    for (int j = 0; j < 16; ++j) {
        const int mr = j * 4 + rg;
        tile[lc][mr] = f2bfu(xp[(size_t)mr * TD + lc]);
    }
    __syncthreads();
    u16* op = XbT + (size_t)cg * KDIM + m0;
    #pragma unroll
    for (int j = 0; j < 16; ++j) {
        const int cr = j * 4 + rg;
        const int ls = ((((lc >> 3) ^ cr) & 7) << 3) | (lc & 7);
        op[(size_t)cr * KDIM + ls] = tile[cr][lc];
    }
}

// ---------------------------------------------------------------------------
// gphase<MIH,LOADB>: one m201-style phase — issue ds_reads (bg optional + 4
// af), BARRIER (stagger issue across waves), lgkmcnt(0)+sched fence (rule
// #18), setprio-wrapped 16-MFMA cluster, closing barrier. All acc indices
// compile-time (rule #20).
// ---------------------------------------------------------------------------
template <int MIH, bool LOADB>
__device__ __forceinline__ void gphase(const char* Ab, const char* Bb, int koff,
                                       int arow0, int brow0,
                                       f32x4 (*acc)[4], bf16x8* bg)
{
    if (LOADB) {
        #pragma unroll
        for (int ni = 0; ni < 4; ++ni)
            bg[ni] = *(const bf16x8*)(Bb + (brow0 + ni * 16) * 128 + koff);
    }
    bf16x8 af[4];
    #pragma unroll
    for (int mi = 0; mi < 4; ++mi)
        af[mi] = *(const bf16x8*)(Ab + (arow0 + (MIH * 4 + mi) * 16) * 128 + koff);
    __builtin_amdgcn_s_barrier();   // all waves' reads in flight before waits
    asm volatile("s_waitcnt lgkmcnt(0)" ::: "memory");
    __builtin_amdgcn_sched_barrier(0);
    __builtin_amdgcn_s_setprio(1);
    #pragma unroll
    for (int mi = 0; mi < 4; ++mi)
        #pragma unroll
        for (int ni = 0; ni < 4; ++ni)
            acc[MIH * 4 + mi][ni] = __builtin_amdgcn_mfma_f32_16x16x32_bf16(
                af[mi], bg[ni], acc[MIH * 4 + mi][ni], 0, 0, 0);
    __builtin_amdgcn_s_setprio(0);
    __builtin_amdgcn_sched_barrier(0);
    __builtin_amdgcn_s_barrier();
}

// ---------------------------------------------------------------------------
// gemm256<MODE>: 256x256 tile, BK=64, 8 waves (2Mx4N), 128KiB LDS dbuf,
// 4-phase-per-K-tile m201-template schedule (T2+T3+T4+T5): per tile,
// phases (mi-half x kh) each {reads | bar | lgkm(0) | prio MFMA | bar};
// bg(kh) loaded once per kh, reused across mi-half phases. Tile-granular
// staging with counted vmcnt(8) between tiles (never 0 in steady state).
//   Out[m][c] = sum_k A[m][k]*B[c][k]; A,B stored chunk-swizzled by row&7.
//   MODE 0 (tcheb): O1[m][swz(c,m)] = bf16(2*acc - (m==c))     [M=N=2048]
//   MODE 1 (Y):     m<2048 -> O1[m][c]=bf16(acc) (Y1row)
//                   m>=2048 -> O2[m-2048][c]=bf16(acc) (Y2row)  [M=4096]
// ---------------------------------------------------------------------------
template <int MODE>
__launch_bounds__(512, 2)
__global__ void gemm256(const u16* __restrict__ A, const u16* __restrict__ B,
                        u16* __restrict__ O1, u16* __restrict__ O2)
{
    __shared__ char smem[131072];   // [2 buf][A 32K | B 32K]
    const int tid = threadIdx.x;
    const int lane = tid & 63;
    const int w = tid >> 6;                 // 0..7
    const int wm = w >> 2, wn = w & 3;      // 2 x 4 waves
    const int ln15 = lane & 15, quad = lane >> 4;

    const int m0 = blockIdx.y * 256;
    const int c0 = blockIdx.x * 256;

    // staging: per K-tile, wave w stages A row-groups {w*4..w*4+3} and same
    // for B; each group = 8 rows x 64k (1KB issue, linear dest).
    const int srow = lane >> 3;             // 0..7
    const int sbyte = (lane & 7) * 16;
    const char* gA = (const char*)A + (size_t)(m0 + w * 32 + srow) * 4096 + sbyte;
    const char* gB = (const char*)B + (size_t)(c0 + w * 32 + srow) * 4096 + sbyte;
    char* lA = smem + w * 4096;             // + buf*65536 + j*1024
    char* lB = smem + 32768 + w * 4096;

    auto stage = [&](int t, int buf) {
        #pragma unroll
        for (int j = 0; j < 4; ++j) {
            gl2lds16(gA + (size_t)j * 32768 + (size_t)t * 128,
                     lA + buf * 65536 + j * 1024);
            gl2lds16(gB + (size_t)j * 32768 + (size_t)t * 128,
                     lB + buf * 65536 + j * 1024);
        }
    };

    f32x4 acc[8][4] = {};
    bf16x8 bg[4];
    const int arow0 = wm * 128 + ln15;      // + mi*16
    const int brow0 = wn * 64 + ln15;       // + ni*16
    const int xorm = (ln15 & 7) << 4;       // read-side chunk XOR

    const int NTI = KDIM / 64;              // 32 K-tiles
    stage(0, 0);                            // prologue: t0 -> buf0
    stage(1, 1);                            //           t1 -> buf1
    asm volatile("s_waitcnt vmcnt(8)" ::: "memory");   // t0 resident
    __builtin_amdgcn_sched_barrier(0);
    __builtin_amdgcn_s_barrier();

    #pragma unroll 1
    for (int t = 0; t < NTI; ++t) {
        const int cur = t & 1;
        const char* Ab = smem + cur * 65536;
        const char* Bb = Ab + 32768;
        const int k0 = (quad * 16) ^ xorm;
        const int k1 = (64 + quad * 16) ^ xorm;

        gphase<0, true >(Ab, Bb, k0, arow0, brow0, acc, bg);
        gphase<1, false>(Ab, Bb, k0, arow0, brow0, acc, bg);
        gphase<0, true >(Ab, Bb, k1, arow0, brow0, acc, bg);
        gphase<1, false>(Ab, Bb, k1, arow0, brow0, acc, bg);
        // buf[cur] fully read (last phase barrier) -> refill with t+2
        if (t + 2 < NTI) {
            stage(t + 2, cur);
            asm volatile("s_waitcnt vmcnt(8)" ::: "memory"); // t+1 resident
        } else {
            asm volatile("s_waitcnt vmcnt(0)" ::: "memory");
        }
        __builtin_amdgcn_sched_barrier(0);
        __builtin_amdgcn_s_barrier();       // buf[(t+1)&1] ready for all
    }

    // epilogue: C/D layout col = lane&15, row = quad*4 + reg
    const int mbase = m0 + wm * 128 + quad * 4;
    const int cbase = c0 + wn * 64 + ln15;
    if (MODE == 0) {
        #pragma unroll
        for (int mi = 0; mi < 8; ++mi) {
            #pragma unroll
            for (int ni = 0; ni < 4; ++ni) {
                const f32x4 v = acc[mi][ni];
                const int cc = cbase + ni * 16;
                #pragma unroll
                for (int r = 0; r < 4; ++r) {
                    const int mm = mbase + mi * 16 + r;
                    const float t2 = 2.f * v[r] - ((mm == cc) ? 1.f : 0.f);
                    O1[(size_t)mm * KDIM + cswz(cc, mm)] = f2bfu(t2);
                }
            }
        }
    } else {
        u16* Ob = (m0 < 2048) ? O1 : O2;
        const int mb = (m0 < 2048) ? mbase : (mbase - 2048);
        #pragma unroll
        for (int mi = 0; mi < 8; ++mi) {
            #pragma unroll
            for (int ni = 0; ni < 4; ++ni) {
                const f32x4 v = acc[mi][ni];
                const int cc = cbase + ni * 16;
                u16* orow = Ob + (size_t)(mb + mi * 16) * C_COLS + cc;
                orow[0 * C_COLS] = f2bfu(v.x);
                orow[1 * C_COLS] = f2bfu(v.y);
                orow[2 * C_COLS] = f2bfu(v.z);
                orow[3 * C_COLS] = f2bfu(v.w);
            }
        }
    }
}

// ---------------------------------------------------------------------------
// Kernel 3 (old path): bf16 MFMA GEMM, 128x128 tile, BK=32.
// ---------------------------------------------------------------------------
template <int MODE>
__launch_bounds__(256, 3)
__global__ void mfma_gemm(const u16* __restrict__ A,
                          const u16* __restrict__ B,
                          u16* __restrict__ OutT,
                          u16* __restrict__ OutRow,
                          const u16* __restrict__ Xc,
                          int c0g)
{
    __shared__ char smem[16384];
    char* As = smem;
    char* Bs = smem + 8192;

    const int tid = threadIdx.x;
    const int lane = tid & 63;
    const int w = tid >> 6;
    const int wm = w >> 1, wn = w & 1;
    const int ln15 = lane & 15, quad = lane >> 4;

    const int m0 = blockIdx.y * 128;
    const int cb = blockIdx.x * 128;

    const int q0 = 2 * w, q1 = 2 * w + 1;
    const int srow = lane >> 2;
    const int skol = (lane & 3) * 8;
    const u16* ga0 = A + (size_t)(m0 + q0 * 16 + srow) * KDIM + skol;
    const u16* ga1 = A + (size_t)(m0 + q1 * 16 + srow) * KDIM + skol;
    const u16* gb0 = B + (size_t)(cb + q0 * 16 + srow) * KDIM + skol;
    const u16* gb1 = B + (size_t)(cb + q1 * 16 + srow) * KDIM + skol;
    char* la0 = As + q0 * 1024;
    char* la1 = As + q1 * 1024;
    char* lb0 = Bs + q0 * 1024;
    char* lb1 = Bs + q1 * 1024;

    f32x4 acc[4][4] = {};

    for (int k0 = 0; k0 < KDIM; k0 += 32) {
        __syncthreads();
        gl2lds16(ga0, la0);
        gl2lds16(ga1, la1);
        gl2lds16(gb0, lb0);
        gl2lds16(gb1, lb1);
        ga0 += 32; ga1 += 32; gb0 += 32; gb1 += 32;
        __syncthreads();

        bf16x8 af[4], bg[4];
        #pragma unroll
        for (int i = 0; i < 4; ++i) {
            af[i] = *(const bf16x8*)(As + ((wm * 64 + i * 16 + ln15) * 64 + quad * 16));
            bg[i] = *(const bf16x8*)(Bs + ((wn * 64 + i * 16 + ln15) * 64 + quad * 16));
        }
        #pragma unroll
        for (int mi = 0; mi < 4; ++mi)
            #pragma unroll
            for (int ni = 0; ni < 4; ++ni)
                acc[mi][ni] = __builtin_amdgcn_mfma_f32_16x16x32_bf16(
                    af[mi], bg[ni], acc[mi][ni], 0, 0, 0);
    }

    const int mbase = m0 + wm * 64 + quad * 4;
    const int cbase = cb + wn * 64 + ln15;
    #pragma unroll
    for (int mi = 0; mi < 4; ++mi) {
        #pragma unroll
        for (int ni = 0; ni < 4; ++ni) {
            const f32x4 v = acc[mi][ni];
            const int mm = mbase + mi * 16;
            const int cc = cbase + ni * 16;
            if (MODE == 0) {
                ushort4 u;
                u.x = f2bfu(v.x); u.y = f2bfu(v.y); u.z = f2bfu(v.z); u.w = f2bfu(v.w);
                *(ushort4*)(OutT + (size_t)cc * KDIM + mm) = u;
                u16* orow = OutRow + (size_t)mm * C_COLS + c0g + cc;
                orow[0 * C_COLS] = u.x;
                orow[1 * C_COLS] = u.y;
                orow[2 * C_COLS] = u.z;
                orow[3 * C_COLS] = u.w;
            } else {
                const ushort4 xv = *(const ushort4*)(Xc + (size_t)cc * KDIM + mm);
                u16* orow = OutRow + (size_t)mm * C_COLS + c0g + cc;
                orow[0 * C_COLS] = f2bfu(2.f * v.x - bfu2f(xv.x));
                orow[1 * C_COLS] = f2bfu(2.f * v.y - bfu2f(xv.y));
                orow[2 * C_COLS] = f2bfu(2.f * v.z - bfu2f(xv.z));
                orow[3 * C_COLS] = f2bfu(2.f * v.w - bfu2f(xv.w));
            }
        }
    }
}

// ---------------------------------------------------------------------------
// Kernel W1: whyper — Wrow[n][ki][o] = bf16( sum_d E[n][d] * Wp[d][ki*64+o] )
// ---------------------------------------------------------------------------
__launch_bounds__(256, 2)
__global__ void whyper_kernel(const float* __restrict__ E,
                              const float* __restrict__ Wp,
                              u16* __restrict__ Wrow)
{
    __shared__ float Es[32][16];
    const int tid = threadIdx.x;
    const int kt = blockIdx.x;
    const int n0 = blockIdx.y * 32;
    for (int i = tid; i < 512; i += 256)
        Es[i >> 4][i & 15] = E[(n0 + (i >> 4)) * EMB + (i & 15)];
    __syncthreads();

    const int o = tid & 63;
    const int kq = tid >> 6;
    #pragma unroll 1
    for (int it = 0; it < 6; ++it) {
        const int ki = kt * 24 + it * 4 + kq;
        const float* wp = Wp + (size_t)ki * 64 + o;
        float wv[EMB];
        #pragma unroll
        for (int d = 0; d < EMB; ++d) wv[d] = wp[(size_t)d * 12288];
        #pragma unroll 4
        for (int nn = 0; nn < 32; ++nn) {
            float a = 0.f;
            #pragma unroll
            for (int d = 0; d < EMB; ++d) a = fmaf(Es[nn][d], wv[d], a);
            Wrow[(size_t)(n0 + nn) * 12288 + (size_t)ki * 64 + o] = f2bfu(a);
        }
    }
}

// ---------------------------------------------------------------------------
// Kernel W2: wtrans — in-place per-node transpose Wrow[n][ki][o] ->
//   Wall[n][o][ki], XOR-swizzled: byte = o*384 + ((ki*2) ^ ((o&7)<<4)).
// ---------------------------------------------------------------------------
__launch_bounds__(256, 2)
__global__ void wtrans_kernel(u16* __restrict__ Wbuf)
{
    __shared__ u16 Wt[64 * 192];
    const int n = blockIdx.x;
    const int tid = threadIdx.x;
    u16* Wn = Wbuf + (size_t)n * 12288;

    ushort4 va[6][2];
    #pragma unroll
    for (int j = 0; j < 6; ++j) {
        const int c = tid + j * 256;
        va[j][0] = *(const ushort4*)(Wn + c * 8);
        va[j][1] = *(const ushort4*)(Wn + c * 8 + 4);
    }
    #pragma unroll
    for (int j = 0; j < 6; ++j) {
        const int c = tid + j * 256;
        const int ki = c >> 3;
        const int o0 = (c & 7) * 8;
        Wt[(o0 + 0) * 192 + ki] = va[j][0].x;
        Wt[(o0 + 1) * 192 + ki] = va[j][0].y;
        Wt[(o0 + 2) * 192 + ki] = va[j][0].z;
        Wt[(o0 + 3) * 192 + ki] = va[j][0].w;
        Wt[(o0 + 4) * 192 + ki] = va[j][1].x;
        Wt[(o0 + 5) * 192 + ki] = va[j][1].y;
        Wt[(o0 + 6) * 192 + ki] = va[j][1].z;
        Wt[(o0 + 7) * 192 + ki] = va[j][1].w;
    }
    __syncthreads();

    #pragma unroll
    for (int j = 0; j < 6; ++j) {
        const int c = tid + j * 256;
        const int o = c / 24;
        const int kc = c - o * 24;
        const int ki0 = kc * 8;
        const int m = (o & 7) << 4;
        const ushort4 lo = *(const ushort4*)(Wt + o * 192 + ki0);
        const ushort4 hi = *(const ushort4*)(Wt + o * 192 + ki0 + 4);
        char* gp = (char*)Wbuf + (size_t)n * 24576 + o * 384 + ((ki0 * 2) ^ m);
        *(ushort4*)gp = lo;
        *(ushort4*)(gp + 8) = hi;
    }
}

// ---------------------------------------------------------------------------
// Kernel 4: per-node gconv via MFMA, W from precomputed swizzled Wall.
// ---------------------------------------------------------------------------
__launch_bounds__(256, 4)
__global__ void gconv_mfma2_kernel(const float* __restrict__ x,
                                   const float* __restrict__ E,
                                   const float* __restrict__ Bp,
                                   const u16* __restrict__ Wall,
                                   const u16* __restrict__ Y1,
                                   const u16* __restrict__ Y2,
                                   float* __restrict__ Out)
{
    __shared__ char WsB[24576];
    __shared__ float en[EMB];
    __shared__ float bias[64];

    const int n = blockIdx.x;
    const int tid = threadIdx.x;
    const int lane = tid & 63;
    const int w = tid >> 6;

    if (tid < EMB) en[tid] = E[n * EMB + tid];

    const char* Wn = (const char*)Wall + (size_t)n * 24576;
    for (int iss = w; iss < 24; iss += 4)
        gl2lds16(Wn + iss * 1024 + lane * 16, WsB + iss * 1024);

    __syncthreads();

    if (tid < 64) {
        float a = 0.f;
        #pragma unroll
        for (int d = 0; d < EMB; ++d) a = fmaf(en[d], Bp[d * 64 + tid], a);
        bias[tid] = a;
    }
    __syncthreads();

    const int ln15 = lane & 15, quad = lane >> 4;
    const int q16 = quad * 16;
    const int m0w = w * 48;

    int rowb[4], msk[4];
    #pragma unroll
    for (int ni = 0; ni < 4; ++ni) {
        const int o = ni * 16 + ln15;
        rowb[ni] = o * 384;
        msk[ni] = (o & 7) << 4;
    }

    const float* xb[3];
    size_t yo[3];
    #pragma unroll
    for (int mi = 0; mi < 3; ++mi) {
        const int bt = m0w + mi * 16 + ln15;
        const int b = bt / NT, t = bt - b * NT;
        xb[mi] = x + (size_t)b * BSTRIDE + (size_t)n * TD + (size_t)t * 64 + quad * 8;
        yo[mi] = (size_t)n * C_COLS + (size_t)bt * 64 + quad * 8;
    }

    f32x4 acc[3][4] = {};

    #pragma unroll
    for (int ks = 0; ks < 2; ++ks) {
        bf16x8 af[3];
        #pragma unroll
        for (int mi = 0; mi < 3; ++mi) {
            const float* p = xb[mi] + ks * 32;
            const f32x4 lo = *(const f32x4*)p;
            const f32x4 hi = *(const f32x4*)(p + 4);
            u16x8 u;
            u[0] = f2bfu(lo.x); u[1] = f2bfu(lo.y); u[2] = f2bfu(lo.z); u[3] = f2bfu(lo.w);
            u[4] = f2bfu(hi.x); u[5] = f2bfu(hi.y); u[6] = f2bfu(hi.z); u[7] = f2bfu(hi.w);
            af[mi] = *(const bf16x8*)&u;
        }
        bf16x8 bg[4];
        #pragma unroll
        for (int ni = 0; ni < 4; ++ni)
            bg[ni] = *(const bf16x8*)(WsB + rowb[ni] + ((ks * 64 + q16) ^ msk[ni]));
        #pragma unroll
        for (int mi = 0; mi < 3; ++mi)
            #pragma unroll
            for (int ni = 0; ni < 4; ++ni)
                acc[mi][ni] = __builtin_amdgcn_mfma_f32_16x16x32_bf16(
                    af[mi], bg[ni], acc[mi][ni], 0, 0, 0);
    }

    const u16* ybase[2] = { Y1, Y2 };
    #pragma unroll
    for (int s = 0; s < 2; ++s) {
        const u16* Yb = ybase[s];
        #pragma unroll
        for (int ks = 0; ks < 2; ++ks) {
            bf16x8 af[3];
            #pragma unroll
            for (int mi = 0; mi < 3; ++mi)
                af[mi] = *(const bf16x8*)(Yb + yo[mi] + ks * 32);
            bf16x8 bg[4];
            #pragma unroll
            for (int ni = 0; ni < 4; ++ni)
                bg[ni] = *(const bf16x8*)(WsB + rowb[ni] + 128 + s * 128
                                          + ((ks * 64 + q16) ^ msk[ni]));
            #pragma unroll
            for (int mi = 0; mi < 3; ++mi)
                #pragma unroll
                for (int ni = 0; ni < 4; ++ni)
                    acc[mi][ni] = __builtin_amdgcn_mfma_f32_16x16x32_bf16(
                        af[mi], bg[ni], acc[mi][ni], 0, 0, 0);
        }
    }

    float bv[4];
    #pragma unroll
    for (int ni = 0; ni < 4; ++ni) bv[ni] = bias[ni * 16 + ln15];

    #pragma unroll
    for (int mi = 0; mi < 3; ++mi) {
        const int rowb2 = m0w + mi * 16 + quad * 4;
        #pragma unroll
        for (int r = 0; r < 4; ++r) {
            const int bt = rowb2 + r;
            const int b = bt / NT, t = bt - b * NT;
            float* op = Out + (((size_t)(b * N_NODES + n)) * NT + t) * 64 + ln15;
            #pragma unroll
            for (int ni = 0; ni < 4; ++ni)
                op[ni * 16] = acc[mi][ni][r] + bv[ni];
        }
    }
}

// ---------------------------------------------------------------------------
// Kernel 4 (fallback): fused hypernet gconv.
// ---------------------------------------------------------------------------
__launch_bounds__(256, 4)
__global__ void gconv_mfma_kernel(const float* __restrict__ x,
                                  const float* __restrict__ E,
                                  const float* __restrict__ Wp,
                                  const float* __restrict__ Bp,
                                  const u16* __restrict__ Y1,
                                  const u16* __restrict__ Y2,
                                  float* __restrict__ Out)
{
    __shared__ u16 Ws[64][200];
    __shared__ float en[EMB];
    __shared__ float bias[64];

    const int n = blockIdx.x;
    const int tid = threadIdx.x;
    if (tid < EMB) en[tid] = E[n * EMB + tid];
    __syncthreads();

    {
        const int o = tid & 63;
        const int kio = tid >> 6;
        #pragma unroll 4
        for (int j = 0; j < 48; ++j) {
            const int ki = j * 4 + kio;
            const float* wp = Wp + ki * 64 + o;
            float a = 0.f;
            #pragma unroll
            for (int d = 0; d < EMB; ++d) a = fmaf(en[d], wp[d * 12288], a);
            Ws[o][ki] = f2bfu(a);
        }
        if (tid < 64) {
            float a = 0.f;
            #pragma unroll
            for (int d = 0; d < EMB; ++d) a = fmaf(en[d], Bp[d * 64 + tid], a);
            bias[tid] = a;
        }
    }
    __syncthreads();

    const int lane = tid & 63;
    const int w = tid >> 6;
    const int ln15 = lane & 15, quad = lane >> 4;
    const int m0w = w * 48;

    const float* xb[3];
    size_t yo[3];
    #pragma unroll
    for (int mi = 0; mi < 3; ++mi) {
        const int bt = m0w + mi * 16 + ln15;
        const int b = bt / NT, t = bt - b * NT;
        xb[mi] = x + (size_t)b * BSTRIDE + (size_t)n * TD + (size_t)t * 64 + quad * 8;
        yo[mi] = (size_t)n * C_COLS + (size_t)bt * 64 + quad * 8;
    }

    f32x4 acc[3][4] = {};

    #pragma unroll
    for (int ks = 0; ks < 2; ++ks) {
        bf16x8 af[3];
        #pragma unroll
        for (int mi = 0; mi < 3; ++mi) {
            const float* p = xb[mi] + ks * 32;
            const f32x4 lo = *(const f32x4*)p;
            const f32x4 hi = *(const f32x4*)(p + 4);
            u16x8 u;
            u[0] = f2bfu(lo.x); u[1] = f2bfu(lo.y); u[2] = f2bfu(lo.z); u[3] = f2bfu(lo.w);
            u[4] = f2bfu(hi.x); u[5] = f2bfu(hi.y); u[6] = f2bfu(hi.z); u[7] = f2bfu(hi.w);
            af[mi] = *(const bf16x8*)&u;
        }
        bf16x8 bg[4];
        #pragma unroll
        for (int ni = 0; ni < 4; ++ni)
            bg[ni] = *(const bf16x8*)&Ws[ni * 16 + ln15][ks * 32 + quad * 8];
        #pragma unroll
        for (int mi = 0; mi < 3; ++mi)
            #pragma unroll
            for (int ni = 0; ni < 4; ++ni)
                acc[mi][ni] = __builtin_amdgcn_mfma_f32_16x16x32_bf16(
                    af[mi], bg[ni], acc[mi][ni], 0, 0, 0);
    }

    const u16* ybase[2] = { Y1, Y2 };
    #pragma unroll
    for (int s = 0; s < 2; ++s) {
        const u16* Yb = ybase[s];
        #pragma unroll
        for (int ks = 0; ks < 2; ++ks) {
            bf16x8 af[3];
            #pragma unroll
            for (int mi = 0; mi < 3; ++mi)
                af[mi] = *(const bf16x8*)(Yb + yo[mi] + ks * 32);
            bf16x8 bg[4];
            #pragma unroll
            for (int ni = 0; ni < 4; ++ni)
                bg[ni] = *(const bf16x8*)&Ws[ni * 16 + ln15][64 + s * 64 + ks * 32 + quad * 8];
            #pragma unroll
            for (int mi = 0; mi < 3; ++mi)
                #pragma unroll
                for (int ni = 0; ni < 4; ++ni)
                    acc[mi][ni] = __builtin_amdgcn_mfma_f32_16x16x32_bf16(
                        af[mi], bg[ni], acc[mi][ni], 0, 0, 0);
        }
    }

    float bv[4];
    #pragma unroll
    for (int ni = 0; ni < 4; ++ni) bv[ni] = bias[ni * 16 + ln15];

    #pragma unroll
    for (int mi = 0; mi < 3; ++mi) {
        const int rowb = m0w + mi * 16 + quad * 4;
        #pragma unroll
        for (int r = 0; r < 4; ++r) {
            const int bt = rowb + r;
            const int b = bt / NT, t = bt - b * NT;
            float* op = Out + (((size_t)(b * N_NODES + n)) * NT + t) * 64 + ln15;
            #pragma unroll
            for (int ni = 0; ni < 4; ++ni)
                op[ni * 16] = acc[mi][ni][r] + bv[ni];
        }
    }
}

// ---------------------------------------------------------------------------
// Workspace (256-scheme, requires ws >= 216 MiB):
//   Sb'   @ 0     (8 MiB)   swizzled bf16 2048x2048      \ contiguous 16 MiB
//   T2b'  @ 8 M   (8 MiB)   swizzled bf16 2S^2-I         /  = A-concat (M=4096)
//   SbT'  @ 16 M  (8 MiB)   swizzled S^T
//   Y1row @ 24 M  (48 MiB)
//   Y2row @ 72 M  (48 MiB)
//   XbT'  @ 120 M (48 MiB)  swizzled
//   Wbuf  @ 168 M (48 MiB)
// Fallback: exact round-2 verified path (chunked 128^2 GEMMs).
// ---------------------------------------------------------------------------
extern "C" void kernel_launch(void* const* d_in, const int* in_sizes, int n_in,
                              void* d_out, int out_size, void* d_ws, size_t ws_size,
                              hipStream_t stream)
{
    const float* x  = (const float*)d_in[0];
    const float* E  = (const float*)d_in[1];
    const float* Wp = (const float*)d_in[2];
    const float* Bp = (const float*)d_in[3];
    float* Out = (float*)d_out;

    const size_t MiB = 1024 * 1024;

    if (ws_size >= 216 * MiB) {
        u16* Sb    = (u16*)d_ws;                          // swizzled
        u16* T2b   = (u16*)((char*)d_ws + 8 * MiB);       // swizzled
        u16* SbT   = (u16*)((char*)d_ws + 16 * MiB);      // swizzled
        u16* Y1row = (u16*)((char*)d_ws + 24 * MiB);
        u16* Y2row = (u16*)((char*)d_ws + 72 * MiB);
        u16* XbT   = (u16*)((char*)d_ws + 120 * MiB);     // swizzled
        u16* Wbuf  = (u16*)((char*)d_ws + 168 * MiB);

        supports2_kernel<<<N_NODES, 256, 0, stream>>>(E, Sb);
        strans_kernel<<<dim3(32, 32), 256, 0, stream>>>(Sb, SbT);
        gemm256<0><<<dim3(8, 8), 512, 0, stream>>>(Sb, SbT, T2b, nullptr);
        xcast2_kernel<<<dim3(192, 32), 256, 0, stream>>>(x, XbT);
        gemm256<1><<<dim3(48, 16), 512, 0, stream>>>(Sb, XbT, Y1row, Y2row);

        whyper_kernel<<<dim3(8, 64), 256, 0, stream>>>(E, Wp, Wbuf);
        wtrans_kernel<<<N_NODES, 256, 0, stream>>>(Wbuf);
        gconv_mfma2_kernel<<<N_NODES, 256, 0, stream>>>(x, E, Bp, Wbuf, Y1row, Y2row, Out);
        return;
    }

    // ---------------- fallback: round-2 verified path ----------------
    u16* Sb    = (u16*)d_ws;
    u16* Y1row = (u16*)((char*)d_ws + 8 * MiB);
    u16* Y2row = (u16*)((char*)d_ws + 56 * MiB);
    char* chunkbase = (char*)d_ws + 104 * MiB;

    size_t wall_off = 0;
    bool newpath = false;
    if (ws_size >= 160 * MiB) {
        wall_off = ((ws_size - 48 * MiB) / 256) * 256;
        if (wall_off >= 112 * MiB) newpath = true;
    }
    const size_t budget = newpath ? wall_off : ws_size;

    const int cands[5] = {1, 2, 3, 6, 12};
    int nc = 12;
    for (int i = 0; i < 5; ++i) {
        const size_t chunk_bytes = (size_t)(C_COLS / cands[i]) * KDIM * 2;
        if (104 * MiB + 2 * chunk_bytes <= budget) { nc = cands[i]; break; }
    }
    const int CW = C_COLS / nc;
    u16* XbTc = (u16*)chunkbase;
    u16* Y1Tc = (u16*)(chunkbase + (size_t)CW * KDIM * 2);
    u16* Wbuf = (u16*)((char*)d_ws + wall_off);

    supports_kernel<<<N_NODES, 256, 0, stream>>>(E, Sb);

    if (newpath) {
        whyper_kernel<<<dim3(8, 64), 256, 0, stream>>>(E, Wp, Wbuf);
        wtrans_kernel<<<N_NODES, 256, 0, stream>>>(Wbuf);
    }

    for (int c = 0; c < nc; ++c) {
        const int c0g = c * CW;
        xcast_kernel<<<dim3(CW / 64, 32), 256, 0, stream>>>(x, XbTc, c0g);
        mfma_gemm<0><<<dim3(CW / 128, 16), 256, 0, stream>>>(Sb, XbTc, Y1Tc, Y1row, nullptr, c0g);
        mfma_gemm<1><<<dim3(CW / 128, 16), 256, 0, stream>>>(Sb, Y1Tc, nullptr, Y2row, XbTc, c0g);
    }

    if (newpath)
        gconv_mfma2_kernel<<<N_NODES, 256, 0, stream>>>(x, E, Bp, Wbuf, Y1row, Y2row, Out);
    else
        gconv_mfma_kernel<<<N_NODES, 256, 0, stream>>>(x, E, Wp, Bp, Y1row, Y2row, Out);
}

// Round 6
// 491.976 us; speedup vs baseline: 1.1419x; 1.1419x over previous
//
#include <hip/hip_runtime.h>
#include <hip/hip_bf16.h>

// Problem constants
#define N_NODES 2048
#define EMB 16
#define NT 12
#define BT 192
#define C_COLS 12288           // BT*64
#define TD 768                 // NT*64, per-(b,node) row length in x
#define BSTRIDE (N_NODES * TD) // per-b stride in x
#define KDIM 2048              // contraction dim (nodes)

typedef unsigned short u16;
typedef unsigned int u32;
typedef __attribute__((ext_vector_type(8))) __bf16 bf16x8;
typedef __attribute__((ext_vector_type(8))) u16 u16x8;
typedef __attribute__((ext_vector_type(4))) float f32x4;

__device__ __forceinline__ u16 f2bfu(float f) { // RNE fp32 -> bf16 bits
    u32 u = __float_as_uint(f);
    return (u16)((u + 0x7FFFu + ((u >> 16) & 1u)) >> 16);
}
__device__ __forceinline__ float bfu2f(u16 h) {
    return __uint_as_float(((u32)h) << 16);
}

// async 16B global->LDS (lds dest = wave-uniform base + lane*16)
__device__ __forceinline__ void gl2lds16(const void* g, void* l) {
    __builtin_amdgcn_global_load_lds(
        (const __attribute__((address_space(1))) u32*)g,
        (__attribute__((address_space(3))) u32*)l, 16, 0, 0);
}

// chunk swizzle: permute 16B chunks within each 128B (64-elem) block by row&7
__device__ __forceinline__ int cswz(int col, int row) {
    return (col & ~63) | ((((col >> 3) ^ row) & 7) << 3) | (col & 7);
}

// ---------------------------------------------------------------------------
// Kernel 1 (old path): Sb[n][m] = bf16( softmax_m( relu( E[n]·E[m] ) ) )
// ---------------------------------------------------------------------------
__global__ void supports_kernel(const float* __restrict__ E, u16* __restrict__ Sb)
{
    __shared__ float en[EMB];
    __shared__ float red[256];
    const int n = blockIdx.x;
    const int tid = threadIdx.x;
    if (tid < EMB) en[tid] = E[n * EMB + tid];
    __syncthreads();

    float v[8];
    float mx = 0.0f;
    #pragma unroll
    for (int j = 0; j < 8; ++j) {
        const int m = tid + j * 256;
        const float* em = E + m * EMB;
        float acc = 0.f;
        #pragma unroll
        for (int d = 0; d < EMB; ++d) acc += en[d] * em[d];
        acc = fmaxf(acc, 0.f);
        v[j] = acc;
        mx = fmaxf(mx, acc);
    }
    red[tid] = mx;
    __syncthreads();
    for (int s = 128; s > 0; s >>= 1) {
        if (tid < s) red[tid] = fmaxf(red[tid], red[tid + s]);
        __syncthreads();
    }
    mx = red[0];
    __syncthreads();

    float sum = 0.f;
    #pragma unroll
    for (int j = 0; j < 8; ++j) { v[j] = __expf(v[j] - mx); sum += v[j]; }
    red[tid] = sum;
    __syncthreads();
    for (int s = 128; s > 0; s >>= 1) {
        if (tid < s) red[tid] += red[tid + s];
        __syncthreads();
    }
    const float inv = 1.f / red[0];
    #pragma unroll
    for (int j = 0; j < 8; ++j)
        Sb[(size_t)n * KDIM + tid + j * 256] = f2bfu(v[j] * inv);
}

// ---------------------------------------------------------------------------
// Kernel 1b (256-scheme): same, but stores chunk-swizzled by n&7.
// ---------------------------------------------------------------------------
__global__ void supports2_kernel(const float* __restrict__ E, u16* __restrict__ Sb)
{
    __shared__ float en[EMB];
    __shared__ float red[256];
    const int n = blockIdx.x;
    const int tid = threadIdx.x;
    if (tid < EMB) en[tid] = E[n * EMB + tid];
    __syncthreads();

    float v[8];
    float mx = 0.0f;
    #pragma unroll
    for (int j = 0; j < 8; ++j) {
        const int m = tid + j * 256;
        const float* em = E + m * EMB;
        float acc = 0.f;
        #pragma unroll
        for (int d = 0; d < EMB; ++d) acc += en[d] * em[d];
        acc = fmaxf(acc, 0.f);
        v[j] = acc;
        mx = fmaxf(mx, acc);
    }
    red[tid] = mx;
    __syncthreads();
    for (int s = 128; s > 0; s >>= 1) {
        if (tid < s) red[tid] = fmaxf(red[tid], red[tid + s]);
        __syncthreads();
    }
    mx = red[0];
    __syncthreads();

    float sum = 0.f;
    #pragma unroll
    for (int j = 0; j < 8; ++j) { v[j] = __expf(v[j] - mx); sum += v[j]; }
    red[tid] = sum;
    __syncthreads();
    for (int s = 128; s > 0; s >>= 1) {
        if (tid < s) red[tid] += red[tid + s];
        __syncthreads();
    }
    const float inv = 1.f / red[0];
    #pragma unroll
    for (int j = 0; j < 8; ++j) {
        const int m = tid + j * 256;
        Sb[(size_t)n * KDIM + cswz(m, n)] = f2bfu(v[j] * inv);
    }
}

// ---------------------------------------------------------------------------
// strans: SbT'[j][swz(m,j)] = S[m][j]  (reads swizzled Sb', writes swizzled)
// ---------------------------------------------------------------------------
__global__ void strans_kernel(const u16* __restrict__ Sb, u16* __restrict__ SbT)
{
    __shared__ u16 T[64][65];
    const int tid = threadIdx.x;
    const int n0 = blockIdx.y * 64;
    const int j0 = blockIdx.x * 64;
    const int lc = tid & 63;
    const int rg = tid >> 6;
    #pragma unroll
    for (int j = 0; j < 16; ++j) {
        const int r = j * 4 + rg;                 // row n0+r of Sb'
        const u16 vv = Sb[(size_t)(n0 + r) * KDIM + j0 + lc];
        // true col of stored pos (j0+lc) in row n: involution
        const int jt = ((((lc >> 3) ^ (n0 + r)) & 7) << 3) | (lc & 7);
        T[jt][r] = vv;                            // T[jt][r] = S[n0+r][j0+jt]
    }
    __syncthreads();
    #pragma unroll
    for (int j = 0; j < 16; ++j) {
        const int jj = j * 4 + rg;                // out row j0+jj
        const int cs = ((((lc >> 3) ^ (j0 + jj)) & 7) << 3) | (lc & 7);
        SbT[(size_t)(j0 + jj) * KDIM + n0 + cs] = T[jj][lc];
    }
}

// ---------------------------------------------------------------------------
// Kernel 2 (old path): xcast — XbT[c][m] = bf16(x[b][m][r])
// ---------------------------------------------------------------------------
__global__ void xcast_kernel(const float* __restrict__ x, u16* __restrict__ XbT, int c0g)
{
    __shared__ u16 tile[64][65];
    const int tid = threadIdx.x;
    const int cg = c0g + blockIdx.x * 64;
    const int b = cg / TD;
    const int r0 = cg - b * TD;
    const int m0 = blockIdx.y * 64;
    const float* xp = x + (size_t)b * BSTRIDE + (size_t)m0 * TD + r0;

    const int lc = tid & 63;
    const int rg = tid >> 6;
    #pragma unroll
    for (int j = 0; j < 16; ++j) {
        const int mr = j * 4 + rg;
        tile[lc][mr] = f2bfu(xp[(size_t)mr * TD + lc]);
    }
    __syncthreads();
    u16* op = XbT + (size_t)(blockIdx.x * 64) * KDIM + m0;
    #pragma unroll
    for (int j = 0; j < 16; ++j) {
        const int cr = j * 4 + rg;
        op[(size_t)cr * KDIM + lc] = tile[cr][lc];
    }
}

// ---------------------------------------------------------------------------
// Kernel 2b (256-scheme): xcast with chunk-swizzled output (by c&7).
// ---------------------------------------------------------------------------
__global__ void xcast2_kernel(const float* __restrict__ x, u16* __restrict__ XbT)
{
    __shared__ u16 tile[64][65];
    const int tid = threadIdx.x;
    const int cg = blockIdx.x * 64;
    const int b = cg / TD;
    const int r0 = cg - b * TD;
    const int m0 = blockIdx.y * 64;
    const float* xp = x + (size_t)b * BSTRIDE + (size_t)m0 * TD + r0;

    const int lc = tid & 63;
    const int rg = tid >> 6;
    #pragma unroll
    for (int j = 0; j < 16; ++j) {
        const int mr = j * 4 + rg;
        tile[lc][mr] = f2bfu(xp[(size_t)mr * TD + lc]);
    }
    __syncthreads();
    u16* op = XbT + (size_t)cg * KDIM + m0;
    #pragma unroll
    for (int j = 0; j < 16; ++j) {
        const int cr = j * 4 + rg;
        const int ls = ((((lc >> 3) ^ cr) & 7) << 3) | (lc & 7);
        op[(size_t)cr * KDIM + ls] = tile[cr][lc];
    }
}

// ---------------------------------------------------------------------------
// gemm256<MODE>: 256x256 tile, BK=64, 8 waves (2Mx4N), 128KiB LDS dbuf,
// round-3 verified schedule (best measured): per K-tile, 2 phases
// {12 ds_read; lgkm(0); setprio(1) 32 MFMA setprio(0); bar} + tile-granular
// staging with counted vmcnt(8) (never 0 in steady state).
//   Out[m][c] = sum_k A[m][k]*B[c][k]; A,B stored chunk-swizzled by row&7.
//   MODE 0 (tcheb): O1[m][swz(c,m)] = bf16(2*acc - (m==c))     [M=N=2048]
//   MODE 1 (Y):     m<2048 -> O1[m][c]=bf16(acc) (Y1row)
//                   m>=2048 -> O2[m-2048][c]=bf16(acc) (Y2row)  [M=4096]
// ---------------------------------------------------------------------------
template <int MODE>
__launch_bounds__(512, 2)
__global__ void gemm256(const u16* __restrict__ A, const u16* __restrict__ B,
                        u16* __restrict__ O1, u16* __restrict__ O2)
{
    __shared__ char smem[131072];   // [2 buf][A 32K | B 32K]
    const int tid = threadIdx.x;
    const int lane = tid & 63;
    const int w = tid >> 6;                 // 0..7
    const int wm = w >> 2, wn = w & 3;      // 2 x 4 waves
    const int ln15 = lane & 15, quad = lane >> 4;

    const int m0 = blockIdx.y * 256;
    const int c0 = blockIdx.x * 256;

    // staging: per K-tile, wave w stages A row-groups {w*4..w*4+3} and same
    // for B; each group = 8 rows x 64k (1KB issue, linear dest).
    const int srow = lane >> 3;             // 0..7
    const int sbyte = (lane & 7) * 16;
    const char* gA = (const char*)A + (size_t)(m0 + w * 32 + srow) * 4096 + sbyte;
    const char* gB = (const char*)B + (size_t)(c0 + w * 32 + srow) * 4096 + sbyte;
    char* lA = smem + w * 4096;             // + buf*65536 + j*1024
    char* lB = smem + 32768 + w * 4096;

    auto stage = [&](int t, int buf) {
        #pragma unroll
        for (int j = 0; j < 4; ++j) {
            gl2lds16(gA + (size_t)j * 32768 + (size_t)t * 128,
                     lA + buf * 65536 + j * 1024);
            gl2lds16(gB + (size_t)j * 32768 + (size_t)t * 128,
                     lB + buf * 65536 + j * 1024);
        }
    };

    f32x4 acc[8][4] = {};
    const int arow0 = wm * 128 + ln15;      // + mi*16
    const int brow0 = wn * 64 + ln15;       // + ni*16
    const int xorm = (ln15 & 7) << 4;       // read-side chunk XOR

    // one compute phase: 12 ds_read_b128 + 32 MFMA, setprio-wrapped
    auto phase = [&](const char* Ab, const char* Bb, int kh) {
        const int koff = (kh * 64 + quad * 16) ^ xorm;
        bf16x8 af[8], bg[4];
        #pragma unroll
        for (int mi = 0; mi < 8; ++mi)
            af[mi] = *(const bf16x8*)(Ab + (arow0 + mi * 16) * 128 + koff);
        #pragma unroll
        for (int ni = 0; ni < 4; ++ni)
            bg[ni] = *(const bf16x8*)(Bb + (brow0 + ni * 16) * 128 + koff);
        asm volatile("s_waitcnt lgkmcnt(0)" ::: "memory");
        __builtin_amdgcn_sched_barrier(0);
        __builtin_amdgcn_s_setprio(1);
        #pragma unroll
        for (int mi = 0; mi < 8; ++mi)
            #pragma unroll
            for (int ni = 0; ni < 4; ++ni)
                acc[mi][ni] = __builtin_amdgcn_mfma_f32_16x16x32_bf16(
                    af[mi], bg[ni], acc[mi][ni], 0, 0, 0);
        __builtin_amdgcn_s_setprio(0);
        __builtin_amdgcn_sched_barrier(0);
        __builtin_amdgcn_s_barrier();       // phase end: all waves' reads done
    };

    const char* b0A = smem;
    const char* b0B = smem + 32768;
    const char* b1A = smem + 65536;
    const char* b1B = smem + 98304;

    const int NTI = KDIM / 64;              // 32 K-tiles
    stage(0, 0);                            // prologue: t0 -> buf0
    stage(1, 1);                            //           t1 -> buf1

    #pragma unroll 1
    for (int it = 0; it < NTI / 2; ++it) {
        const int t0 = 2 * it;
        // top: refill buf1 with this iteration's odd tile (freed by prev
        // iteration's last phase barrier); prologue covers it==0.
        if (it > 0) stage(t0 + 1, 1);
        asm volatile("s_waitcnt vmcnt(8)" ::: "memory");   // t0 resident
        __builtin_amdgcn_sched_barrier(0);
        __builtin_amdgcn_s_barrier();

        phase(b0A, b0B, 0);                 // tile t0
        phase(b0A, b0B, 1);                 // buf0 free after this barrier

        if (t0 + 2 < NTI) {
            stage(t0 + 2, 0);               // refill buf0 with t0+2
            asm volatile("s_waitcnt vmcnt(8)" ::: "memory"); // t0+1 resident
        } else {
            asm volatile("s_waitcnt vmcnt(0)" ::: "memory");
        }
        __builtin_amdgcn_sched_barrier(0);
        __builtin_amdgcn_s_barrier();

        phase(b1A, b1B, 0);                 // tile t0+1
        phase(b1A, b1B, 1);                 // buf1 free after this barrier
    }

    // epilogue: C/D layout col = lane&15, row = quad*4 + reg
    const int mbase = m0 + wm * 128 + quad * 4;
    const int cbase = c0 + wn * 64 + ln15;
    if (MODE == 0) {
        #pragma unroll
        for (int mi = 0; mi < 8; ++mi) {
            #pragma unroll
            for (int ni = 0; ni < 4; ++ni) {
                const f32x4 v = acc[mi][ni];
                const int cc = cbase + ni * 16;
                #pragma unroll
                for (int r = 0; r < 4; ++r) {
                    const int mm = mbase + mi * 16 + r;
                    const float t2 = 2.f * v[r] - ((mm == cc) ? 1.f : 0.f);
                    O1[(size_t)mm * KDIM + cswz(cc, mm)] = f2bfu(t2);
                }
            }
        }
    } else {
        u16* Ob = (m0 < 2048) ? O1 : O2;
        const int mb = (m0 < 2048) ? mbase : (mbase - 2048);
        #pragma unroll
        for (int mi = 0; mi < 8; ++mi) {
            #pragma unroll
            for (int ni = 0; ni < 4; ++ni) {
                const f32x4 v = acc[mi][ni];
                const int cc = cbase + ni * 16;
                u16* orow = Ob + (size_t)(mb + mi * 16) * C_COLS + cc;
                orow[0 * C_COLS] = f2bfu(v.x);
                orow[1 * C_COLS] = f2bfu(v.y);
                orow[2 * C_COLS] = f2bfu(v.z);
                orow[3 * C_COLS] = f2bfu(v.w);
            }
        }
    }
}

// ---------------------------------------------------------------------------
// gemm128s: 128x128 tile for the T2 GEMM (M=N=2048 -> grid 16x16 = 256
// blocks, full CU fill vs 64-block 256^2 launch). Same swizzled operands,
// same round-3 schedule, BK=64 dbuf in 64 KiB LDS (2 blocks/CU possible).
//   O1[m][swz(c,m)] = bf16( 2*sum_k A[m][k]*B[c][k] - (m==c) )
// ---------------------------------------------------------------------------
__launch_bounds__(256, 2)
__global__ void gemm128s(const u16* __restrict__ A, const u16* __restrict__ B,
                         u16* __restrict__ O1)
{
    __shared__ char smem[65536];    // [2 buf][A 16K | B 16K]
    const int tid = threadIdx.x;
    const int lane = tid & 63;
    const int w = tid >> 6;                 // 0..3
    const int wm = w >> 1, wn = w & 1;      // 2 x 2 waves
    const int ln15 = lane & 15, quad = lane >> 4;

    const int m0 = blockIdx.y * 128;
    const int c0 = blockIdx.x * 128;

    // staging: 16 issues of 8 rows x 128 B per operand; wave w does 4 each.
    const int srow = lane >> 3;             // 0..7
    const int sbyte = (lane & 7) * 16;
    const char* gA = (const char*)A + (size_t)(m0 + w * 32 + srow) * 4096 + sbyte;
    const char* gB = (const char*)B + (size_t)(c0 + w * 32 + srow) * 4096 + sbyte;
    char* lA = smem + w * 4096;             // + buf*32768 + j*1024
    char* lB = smem + 16384 + w * 4096;

    auto stage = [&](int t, int buf) {
        #pragma unroll
        for (int j = 0; j < 4; ++j) {
            gl2lds16(gA + (size_t)j * 32768 + (size_t)t * 128,
                     lA + buf * 32768 + j * 1024);
            gl2lds16(gB + (size_t)j * 32768 + (size_t)t * 128,
                     lB + buf * 32768 + j * 1024);
        }
    };

    f32x4 acc[4][4] = {};
    const int arow0 = wm * 64 + ln15;
    const int brow0 = wn * 64 + ln15;
    const int xorm = (ln15 & 7) << 4;

    auto phase = [&](const char* Ab, const char* Bb, int kh) {
        const int koff = (kh * 64 + quad * 16) ^ xorm;
        bf16x8 af[4], bg[4];
        #pragma unroll
        for (int mi = 0; mi < 4; ++mi)
            af[mi] = *(const bf16x8*)(Ab + (arow0 + mi * 16) * 128 + koff);
        #pragma unroll
        for (int ni = 0; ni < 4; ++ni)
            bg[ni] = *(const bf16x8*)(Bb + (brow0 + ni * 16) * 128 + koff);
        asm volatile("s_waitcnt lgkmcnt(0)" ::: "memory");
        __builtin_amdgcn_sched_barrier(0);
        __builtin_amdgcn_s_setprio(1);
        #pragma unroll
        for (int mi = 0; mi < 4; ++mi)
            #pragma unroll
            for (int ni = 0; ni < 4; ++ni)
                acc[mi][ni] = __builtin_amdgcn_mfma_f32_16x16x32_bf16(
                    af[mi], bg[ni], acc[mi][ni], 0, 0, 0);
        __builtin_amdgcn_s_setprio(0);
        __builtin_amdgcn_sched_barrier(0);
        __builtin_amdgcn_s_barrier();
    };

    const int NTI = KDIM / 64;              // 32 K-tiles
    stage(0, 0);
    stage(1, 1);

    #pragma unroll 1
    for (int it = 0; it < NTI / 2; ++it) {
        const int t0 = 2 * it;
        if (it > 0) stage(t0 + 1, 1);
        asm volatile("s_waitcnt vmcnt(8)" ::: "memory");   // t0 resident
        __builtin_amdgcn_sched_barrier(0);
        __builtin_amdgcn_s_barrier();

        phase(smem, smem + 16384, 0);
        phase(smem, smem + 16384, 1);

        if (t0 + 2 < NTI) {
            stage(t0 + 2, 0);
            asm volatile("s_waitcnt vmcnt(8)" ::: "memory"); // t0+1 resident
        } else {
            asm volatile("s_waitcnt vmcnt(0)" ::: "memory");
        }
        __builtin_amdgcn_sched_barrier(0);
        __builtin_amdgcn_s_barrier();

        phase(smem + 32768, smem + 49152, 0);
        phase(smem + 32768, smem + 49152, 1);
    }

    const int mbase = m0 + wm * 64 + quad * 4;
    const int cbase = c0 + wn * 64 + ln15;
    #pragma unroll
    for (int mi = 0; mi < 4; ++mi) {
        #pragma unroll
        for (int ni = 0; ni < 4; ++ni) {
            const f32x4 v = acc[mi][ni];
            const int cc = cbase + ni * 16;
            #pragma unroll
            for (int r = 0; r < 4; ++r) {
                const int mm = mbase + mi * 16 + r;
                const float t2 = 2.f * v[r] - ((mm == cc) ? 1.f : 0.f);
                O1[(size_t)mm * KDIM + cswz(cc, mm)] = f2bfu(t2);
            }
        }
    }
}

// ---------------------------------------------------------------------------
// Kernel 3 (old path): bf16 MFMA GEMM, 128x128 tile, BK=32.
// ---------------------------------------------------------------------------
template <int MODE>
__launch_bounds__(256, 3)
__global__ void mfma_gemm(const u16* __restrict__ A,
                          const u16* __restrict__ B,
                          u16* __restrict__ OutT,
                          u16* __restrict__ OutRow,
                          const u16* __restrict__ Xc,
                          int c0g)
{
    __shared__ char smem[16384];
    char* As = smem;
    char* Bs = smem + 8192;

    const int tid = threadIdx.x;
    const int lane = tid & 63;
    const int w = tid >> 6;
    const int wm = w >> 1, wn = w & 1;
    const int ln15 = lane & 15, quad = lane >> 4;

    const int m0 = blockIdx.y * 128;
    const int cb = blockIdx.x * 128;

    const int q0 = 2 * w, q1 = 2 * w + 1;
    const int srow = lane >> 2;
    const int skol = (lane & 3) * 8;
    const u16* ga0 = A + (size_t)(m0 + q0 * 16 + srow) * KDIM + skol;
    const u16* ga1 = A + (size_t)(m0 + q1 * 16 + srow) * KDIM + skol;
    const u16* gb0 = B + (size_t)(cb + q0 * 16 + srow) * KDIM + skol;
    const u16* gb1 = B + (size_t)(cb + q1 * 16 + srow) * KDIM + skol;
    char* la0 = As + q0 * 1024;
    char* la1 = As + q1 * 1024;
    char* lb0 = Bs + q0 * 1024;
    char* lb1 = Bs + q1 * 1024;

    f32x4 acc[4][4] = {};

    for (int k0 = 0; k0 < KDIM; k0 += 32) {
        __syncthreads();
        gl2lds16(ga0, la0);
        gl2lds16(ga1, la1);
        gl2lds16(gb0, lb0);
        gl2lds16(gb1, lb1);
        ga0 += 32; ga1 += 32; gb0 += 32; gb1 += 32;
        __syncthreads();

        bf16x8 af[4], bg[4];
        #pragma unroll
        for (int i = 0; i < 4; ++i) {
            af[i] = *(const bf16x8*)(As + ((wm * 64 + i * 16 + ln15) * 64 + quad * 16));
            bg[i] = *(const bf16x8*)(Bs + ((wn * 64 + i * 16 + ln15) * 64 + quad * 16));
        }
        #pragma unroll
        for (int mi = 0; mi < 4; ++mi)
            #pragma unroll
            for (int ni = 0; ni < 4; ++ni)
                acc[mi][ni] = __builtin_amdgcn_mfma_f32_16x16x32_bf16(
                    af[mi], bg[ni], acc[mi][ni], 0, 0, 0);
    }

    const int mbase = m0 + wm * 64 + quad * 4;
    const int cbase = cb + wn * 64 + ln15;
    #pragma unroll
    for (int mi = 0; mi < 4; ++mi) {
        #pragma unroll
        for (int ni = 0; ni < 4; ++ni) {
            const f32x4 v = acc[mi][ni];
            const int mm = mbase + mi * 16;
            const int cc = cbase + ni * 16;
            if (MODE == 0) {
                ushort4 u;
                u.x = f2bfu(v.x); u.y = f2bfu(v.y); u.z = f2bfu(v.z); u.w = f2bfu(v.w);
                *(ushort4*)(OutT + (size_t)cc * KDIM + mm) = u;
                u16* orow = OutRow + (size_t)mm * C_COLS + c0g + cc;
                orow[0 * C_COLS] = u.x;
                orow[1 * C_COLS] = u.y;
                orow[2 * C_COLS] = u.z;
                orow[3 * C_COLS] = u.w;
            } else {
                const ushort4 xv = *(const ushort4*)(Xc + (size_t)cc * KDIM + mm);
                u16* orow = OutRow + (size_t)mm * C_COLS + c0g + cc;
                orow[0 * C_COLS] = f2bfu(2.f * v.x - bfu2f(xv.x));
                orow[1 * C_COLS] = f2bfu(2.f * v.y - bfu2f(xv.y));
                orow[2 * C_COLS] = f2bfu(2.f * v.z - bfu2f(xv.z));
                orow[3 * C_COLS] = f2bfu(2.f * v.w - bfu2f(xv.w));
            }
        }
    }
}

// ---------------------------------------------------------------------------
// Kernel W1: whyper — Wrow[n][ki][o] = bf16( sum_d E[n][d] * Wp[d][ki*64+o] )
// ---------------------------------------------------------------------------
__launch_bounds__(256, 2)
__global__ void whyper_kernel(const float* __restrict__ E,
                              const float* __restrict__ Wp,
                              u16* __restrict__ Wrow)
{
    __shared__ float Es[32][16];
    const int tid = threadIdx.x;
    const int kt = blockIdx.x;
    const int n0 = blockIdx.y * 32;
    for (int i = tid; i < 512; i += 256)
        Es[i >> 4][i & 15] = E[(n0 + (i >> 4)) * EMB + (i & 15)];
    __syncthreads();

    const int o = tid & 63;
    const int kq = tid >> 6;
    #pragma unroll 1
    for (int it = 0; it < 6; ++it) {
        const int ki = kt * 24 + it * 4 + kq;
        const float* wp = Wp + (size_t)ki * 64 + o;
        float wv[EMB];
        #pragma unroll
        for (int d = 0; d < EMB; ++d) wv[d] = wp[(size_t)d * 12288];
        #pragma unroll 4
        for (int nn = 0; nn < 32; ++nn) {
            float a = 0.f;
            #pragma unroll
            for (int d = 0; d < EMB; ++d) a = fmaf(Es[nn][d], wv[d], a);
            Wrow[(size_t)(n0 + nn) * 12288 + (size_t)ki * 64 + o] = f2bfu(a);
        }
    }
}

// ---------------------------------------------------------------------------
// Kernel 4: per-node gconv via MFMA. W staged from Wrow [n][ki][o] with
// in-block transpose + XOR swizzle (replaces the wtrans kernel's 96 MiB
// global round-trip): element ki of row o lands at LDS byte
//   o*384 + (((ki>>3) ^ (o&7))<<4) + (ki&7)*2
// — identical mapping to the former wtrans+gl2lds16 path, so the MFMA
// B-fragment reads below are unchanged.
// ---------------------------------------------------------------------------
__launch_bounds__(256, 4)
__global__ void gconv_mfma2_kernel(const float* __restrict__ x,
                                   const float* __restrict__ E,
                                   const float* __restrict__ Bp,
                                   const u16* __restrict__ Wrow,
                                   const u16* __restrict__ Y1,
                                   const u16* __restrict__ Y2,
                                   float* __restrict__ Out)
{
    __shared__ char WsB[24576];
    __shared__ float en[EMB];
    __shared__ float bias[64];

    const int n = blockIdx.x;
    const int tid = threadIdx.x;
    const int lane = tid & 63;
    const int w = tid >> 6;

    if (tid < EMB) en[tid] = E[n * EMB + tid];

    // stage W: coalesced 16B/lane reads of Wrow[n] (ki-major), scatter
    // transposed+swizzled into LDS.
    {
        const u16* Wn = Wrow + (size_t)n * 12288;
        ushort4 va[6][2];
        #pragma unroll
        for (int j = 0; j < 6; ++j) {
            const int c = tid + j * 256;
            va[j][0] = *(const ushort4*)(Wn + c * 8);
            va[j][1] = *(const ushort4*)(Wn + c * 8 + 4);
        }
        #pragma unroll
        for (int j = 0; j < 6; ++j) {
            const int c = tid + j * 256;
            const int ki = c >> 3;          // element ki (0..191)
            const int o0 = (c & 7) * 8;     // 8 consecutive o
            const int kb = ((ki >> 3) << 4) | ((ki & 7) * 2); // pre-XOR byte
            const u16 vals[8] = { va[j][0].x, va[j][0].y, va[j][0].z, va[j][0].w,
                                  va[j][1].x, va[j][1].y, va[j][1].z, va[j][1].w };
            #pragma unroll
            for (int e = 0; e < 8; ++e) {
                const int o = o0 + e;
                *(u16*)(WsB + o * 384 + (kb ^ ((o & 7) << 4))) = vals[e];
            }
        }
    }
    __syncthreads();

    if (tid < 64) {
        float a = 0.f;
        #pragma unroll
        for (int d = 0; d < EMB; ++d) a = fmaf(en[d], Bp[d * 64 + tid], a);
        bias[tid] = a;
    }
    __syncthreads();

    const int ln15 = lane & 15, quad = lane >> 4;
    const int q16 = quad * 16;
    const int m0w = w * 48;

    int rowb[4], msk[4];
    #pragma unroll
    for (int ni = 0; ni < 4; ++ni) {
        const int o = ni * 16 + ln15;
        rowb[ni] = o * 384;
        msk[ni] = (o & 7) << 4;
    }

    const float* xb[3];
    size_t yo[3];
    #pragma unroll
    for (int mi = 0; mi < 3; ++mi) {
        const int bt = m0w + mi * 16 + ln15;
        const int b = bt / NT, t = bt - b * NT;
        xb[mi] = x + (size_t)b * BSTRIDE + (size_t)n * TD + (size_t)t * 64 + quad * 8;
        yo[mi] = (size_t)n * C_COLS + (size_t)bt * 64 + quad * 8;
    }

    f32x4 acc[3][4] = {};

    #pragma unroll
    for (int ks = 0; ks < 2; ++ks) {
        bf16x8 af[3];
        #pragma unroll
        for (int mi = 0; mi < 3; ++mi) {
            const float* p = xb[mi] + ks * 32;
            const f32x4 lo = *(const f32x4*)p;
            const f32x4 hi = *(const f32x4*)(p + 4);
            u16x8 u;
            u[0] = f2bfu(lo.x); u[1] = f2bfu(lo.y); u[2] = f2bfu(lo.z); u[3] = f2bfu(lo.w);
            u[4] = f2bfu(hi.x); u[5] = f2bfu(hi.y); u[6] = f2bfu(hi.z); u[7] = f2bfu(hi.w);
            af[mi] = *(const bf16x8*)&u;
        }
        bf16x8 bg[4];
        #pragma unroll
        for (int ni = 0; ni < 4; ++ni)
            bg[ni] = *(const bf16x8*)(WsB + rowb[ni] + ((ks * 64 + q16) ^ msk[ni]));
        #pragma unroll
        for (int mi = 0; mi < 3; ++mi)
            #pragma unroll
            for (int ni = 0; ni < 4; ++ni)
                acc[mi][ni] = __builtin_amdgcn_mfma_f32_16x16x32_bf16(
                    af[mi], bg[ni], acc[mi][ni], 0, 0, 0);
    }

    const u16* ybase[2] = { Y1, Y2 };
    #pragma unroll
    for (int s = 0; s < 2; ++s) {
        const u16* Yb = ybase[s];
        #pragma unroll
        for (int ks = 0; ks < 2; ++ks) {
            bf16x8 af[3];
            #pragma unroll
            for (int mi = 0; mi < 3; ++mi)
                af[mi] = *(const bf16x8*)(Yb + yo[mi] + ks * 32);
            bf16x8 bg[4];
            #pragma unroll
            for (int ni = 0; ni < 4; ++ni)
                bg[ni] = *(const bf16x8*)(WsB + rowb[ni] + 128 + s * 128
                                          + ((ks * 64 + q16) ^ msk[ni]));
            #pragma unroll
            for (int mi = 0; mi < 3; ++mi)
                #pragma unroll
                for (int ni = 0; ni < 4; ++ni)
                    acc[mi][ni] = __builtin_amdgcn_mfma_f32_16x16x32_bf16(
                        af[mi], bg[ni], acc[mi][ni], 0, 0, 0);
        }
    }

    float bv[4];
    #pragma unroll
    for (int ni = 0; ni < 4; ++ni) bv[ni] = bias[ni * 16 + ln15];

    #pragma unroll
    for (int mi = 0; mi < 3; ++mi) {
        const int rowb2 = m0w + mi * 16 + quad * 4;
        #pragma unroll
        for (int r = 0; r < 4; ++r) {
            const int bt = rowb2 + r;
            const int b = bt / NT, t = bt - b * NT;
            float* op = Out + (((size_t)(b * N_NODES + n)) * NT + t) * 64 + ln15;
            #pragma unroll
            for (int ni = 0; ni < 4; ++ni)
                op[ni * 16] = acc[mi][ni][r] + bv[ni];
        }
    }
}

// ---------------------------------------------------------------------------
// Kernel 4 (fallback): fused hypernet gconv.
// ---------------------------------------------------------------------------
__launch_bounds__(256, 4)
__global__ void gconv_mfma_kernel(const float* __restrict__ x,
                                  const float* __restrict__ E,
                                  const float* __restrict__ Wp,
                                  const float* __restrict__ Bp,
                                  const u16* __restrict__ Y1,
                                  const u16* __restrict__ Y2,
                                  float* __restrict__ Out)
{
    __shared__ u16 Ws[64][200];
    __shared__ float en[EMB];
    __shared__ float bias[64];

    const int n = blockIdx.x;
    const int tid = threadIdx.x;
    if (tid < EMB) en[tid] = E[n * EMB + tid];
    __syncthreads();

    {
        const int o = tid & 63;
        const int kio = tid >> 6;
        #pragma unroll 4
        for (int j = 0; j < 48; ++j) {
            const int ki = j * 4 + kio;
            const float* wp = Wp + ki * 64 + o;
            float a = 0.f;
            #pragma unroll
            for (int d = 0; d < EMB; ++d) a = fmaf(en[d], wp[d * 12288], a);
            Ws[o][ki] = f2bfu(a);
        }
        if (tid < 64) {
            float a = 0.f;
            #pragma unroll
            for (int d = 0; d < EMB; ++d) a = fmaf(en[d], Bp[d * 64 + tid], a);
            bias[tid] = a;
        }
    }
    __syncthreads();

    const int lane = tid & 63;
    const int w = tid >> 6;
    const int ln15 = lane & 15, quad = lane >> 4;
    const int m0w = w * 48;

    const float* xb[3];
    size_t yo[3];
    #pragma unroll
    for (int mi = 0; mi < 3; ++mi) {
        const int bt = m0w + mi * 16 + ln15;
        const int b = bt / NT, t = bt - b * NT;
        xb[mi] = x + (size_t)b * BSTRIDE + (size_t)n * TD + (size_t)t * 64 + quad * 8;
        yo[mi] = (size_t)n * C_COLS + (size_t)bt * 64 + quad * 8;
    }

    f32x4 acc[3][4] = {};

    #pragma unroll
    for (int ks = 0; ks < 2; ++ks) {
        bf16x8 af[3];
        #pragma unroll
        for (int mi = 0; mi < 3; ++mi) {
            const float* p = xb[mi] + ks * 32;
            const f32x4 lo = *(const f32x4*)p;
            const f32x4 hi = *(const f32x4*)(p + 4);
            u16x8 u;
            u[0] = f2bfu(lo.x); u[1] = f2bfu(lo.y); u[2] = f2bfu(lo.z); u[3] = f2bfu(lo.w);
            u[4] = f2bfu(hi.x); u[5] = f2bfu(hi.y); u[6] = f2bfu(hi.z); u[7] = f2bfu(hi.w);
            af[mi] = *(const bf16x8*)&u;
        }
        bf16x8 bg[4];
        #pragma unroll
        for (int ni = 0; ni < 4; ++ni)
            bg[ni] = *(const bf16x8*)&Ws[ni * 16 + ln15][ks * 32 + quad * 8];
        #pragma unroll
        for (int mi = 0; mi < 3; ++mi)
            #pragma unroll
            for (int ni = 0; ni < 4; ++ni)
                acc[mi][ni] = __builtin_amdgcn_mfma_f32_16x16x32_bf16(
                    af[mi], bg[ni], acc[mi][ni], 0, 0, 0);
    }

    const u16* ybase[2] = { Y1, Y2 };
    #pragma unroll
    for (int s = 0; s < 2; ++s) {
        const u16* Yb = ybase[s];
        #pragma unroll
        for (int ks = 0; ks < 2; ++ks) {
            bf16x8 af[3];
            #pragma unroll
            for (int mi = 0; mi < 3; ++mi)
                af[mi] = *(const bf16x8*)(Yb + yo[mi] + ks * 32);
            bf16x8 bg[4];
            #pragma unroll
            for (int ni = 0; ni < 4; ++ni)
                bg[ni] = *(const bf16x8*)&Ws[ni * 16 + ln15][64 + s * 64 + ks * 32 + quad * 8];
            #pragma unroll
            for (int mi = 0; mi < 3; ++mi)
                #pragma unroll
                for (int ni = 0; ni < 4; ++ni)
                    acc[mi][ni] = __builtin_amdgcn_mfma_f32_16x16x32_bf16(
                        af[mi], bg[ni], acc[mi][ni], 0, 0, 0);
        }
    }

    float bv[4];
    #pragma unroll
    for (int ni = 0; ni < 4; ++ni) bv[ni] = bias[ni * 16 + ln15];

    #pragma unroll
    for (int mi = 0; mi < 3; ++mi) {
        const int rowb = m0w + mi * 16 + quad * 4;
        #pragma unroll
        for (int r = 0; r < 4; ++r) {
            const int bt = rowb + r;
            const int b = bt / NT, t = bt - b * NT;
            float* op = Out + (((size_t)(b * N_NODES + n)) * NT + t) * 64 + ln15;
            #pragma unroll
            for (int ni = 0; ni < 4; ++ni)
                op[ni * 16] = acc[mi][ni][r] + bv[ni];
        }
    }
}

// ---------------------------------------------------------------------------
// Workspace (256-scheme, requires ws >= 216 MiB):
//   Sb'   @ 0     (8 MiB)   swizzled bf16 2048x2048      \ contiguous 16 MiB
//   T2b'  @ 8 M   (8 MiB)   swizzled bf16 2S^2-I         /  = A-concat (M=4096)
//   SbT'  @ 16 M  (8 MiB)   swizzled S^T
//   Y1row @ 24 M  (48 MiB)
//   Y2row @ 72 M  (48 MiB)
//   XbT'  @ 120 M (48 MiB)  swizzled
//   Wbuf  @ 168 M (48 MiB)  Wrow [n][ki][o] (whyper output; gconv
//                           transposes+swizzles in-block — no wtrans)
// Fallback: round-2 verified path (chunked 128^2 GEMMs).
// ---------------------------------------------------------------------------
extern "C" void kernel_launch(void* const* d_in, const int* in_sizes, int n_in,
                              void* d_out, int out_size, void* d_ws, size_t ws_size,
                              hipStream_t stream)
{
    const float* x  = (const float*)d_in[0];
    const float* E  = (const float*)d_in[1];
    const float* Wp = (const float*)d_in[2];
    const float* Bp = (const float*)d_in[3];
    float* Out = (float*)d_out;

    const size_t MiB = 1024 * 1024;

    if (ws_size >= 216 * MiB) {
        u16* Sb    = (u16*)d_ws;                          // swizzled
        u16* T2b   = (u16*)((char*)d_ws + 8 * MiB);       // swizzled
        u16* SbT   = (u16*)((char*)d_ws + 16 * MiB);      // swizzled
        u16* Y1row = (u16*)((char*)d_ws + 24 * MiB);
        u16* Y2row = (u16*)((char*)d_ws + 72 * MiB);
        u16* XbT   = (u16*)((char*)d_ws + 120 * MiB);     // swizzled
        u16* Wbuf  = (u16*)((char*)d_ws + 168 * MiB);

        supports2_kernel<<<N_NODES, 256, 0, stream>>>(E, Sb);
        strans_kernel<<<dim3(32, 32), 256, 0, stream>>>(Sb, SbT);
        gemm128s<<<dim3(16, 16), 256, 0, stream>>>(Sb, SbT, T2b);
        xcast2_kernel<<<dim3(192, 32), 256, 0, stream>>>(x, XbT);
        gemm256<1><<<dim3(48, 16), 512, 0, stream>>>(Sb, XbT, Y1row, Y2row);

        whyper_kernel<<<dim3(8, 64), 256, 0, stream>>>(E, Wp, Wbuf);
        gconv_mfma2_kernel<<<N_NODES, 256, 0, stream>>>(x, E, Bp, Wbuf, Y1row, Y2row, Out);
        return;
    }

    // ---------------- fallback: round-2 verified path ----------------
    u16* Sb    = (u16*)d_ws;
    u16* Y1row = (u16*)((char*)d_ws + 8 * MiB);
    u16* Y2row = (u16*)((char*)d_ws + 56 * MiB);
    char* chunkbase = (char*)d_ws + 104 * MiB;

    size_t wall_off = 0;
    bool newpath = false;
    if (ws_size >= 160 * MiB) {
        wall_off = ((ws_size - 48 * MiB) / 256) * 256;
        if (wall_off >= 112 * MiB) newpath = true;
    }
    const size_t budget = newpath ? wall_off : ws_size;

    const int cands[5] = {1, 2, 3, 6, 12};
    int nc = 12;
    for (int i = 0; i < 5; ++i) {
        const size_t chunk_bytes = (size_t)(C_COLS / cands[i]) * KDIM * 2;
        if (104 * MiB + 2 * chunk_bytes <= budget) { nc = cands[i]; break; }
    }
    const int CW = C_COLS / nc;
    u16* XbTc = (u16*)chunkbase;
    u16* Y1Tc = (u16*)(chunkbase + (size_t)CW * KDIM * 2);
    u16* Wbuf = (u16*)((char*)d_ws + wall_off);

    supports_kernel<<<N_NODES, 256, 0, stream>>>(E, Sb);

    if (newpath) {
        whyper_kernel<<<dim3(8, 64), 256, 0, stream>>>(E, Wp, Wbuf);
    }

    for (int c = 0; c < nc; ++c) {
        const int c0g = c * CW;
        xcast_kernel<<<dim3(CW / 64, 32), 256, 0, stream>>>(x, XbTc, c0g);
        mfma_gemm<0><<<dim3(CW / 128, 16), 256, 0, stream>>>(Sb, XbTc, Y1Tc, Y1row, nullptr, c0g);
        mfma_gemm<1><<<dim3(CW / 128, 16), 256, 0, stream>>>(Sb, Y1Tc, nullptr, Y2row, XbTc, c0g);
    }

    if (newpath)
        gconv_mfma2_kernel<<<N_NODES, 256, 0, stream>>>(x, E, Bp, Wbuf, Y1row, Y2row, Out);
    else
        gconv_mfma_kernel<<<N_NODES, 256, 0, stream>>>(x, E, Wp, Bp, Y1row, Y2row, Out);
}